// Round 16
// baseline (152.654 us; speedup 1.0000x reference)
//
#include <hip/hip_runtime.h>
#include <hip/hip_fp16.h>

#define N_NODES 100000
#define N_EDGES 1600000
#define NFEAT 128
#define NHID 64
#define NCLASS 16

#define NPB 98                     // dst-nodes per bucket
#define NB 1024                    // ceil(100000 / 98) = 1021 -> pad to 1024
#define HIST_EPT 16
#define HIST_BLOCKS ((N_EDGES + 256 * HIST_EPT - 1) / (256 * HIST_EPT))  // 391
#define FILL_EPT 16
#define FILL_BLOCKS ((N_EDGES + 256 * FILL_EPT - 1) / (256 * FILL_EPT))  // 391
#define NTILES ((N_NODES + 15) / 16)            // 6250
#define GEMM_BLOCKS ((NTILES + 3) / 4)          // 1563
#define EPS_CAP 1024               // LDS edge-stage capacity (4-node range; avg 64)

typedef unsigned int u32;
typedef __attribute__((ext_vector_type(8))) _Float16 f16x8;
typedef __attribute__((ext_vector_type(4))) float f32x4;

__device__ __forceinline__ __half2 u2h2(u32 u) { __half2 h; __builtin_memcpy(&h, &u, 4); return h; }
__device__ __forceinline__ u32 h22u(__half2 h) { u32 u; __builtin_memcpy(&u, &h, 4); return u; }
__device__ __forceinline__ u32 pack_h16(float a, float b) { return h22u(__floats2half2_rn(a, b)); }

// per-block edge-index dtype detection: odd u32 of first 64 int64 slots are all
// zero iff data is int64 (node ids < 2^31).
__device__ __forceinline__ int detect_i32(const void* ei) {
    u32 v = ((const u32*)ei)[2 * (threadIdx.x & 63) + 1];
    return (__ballot(v != 0) != 0ULL) ? 1 : 0;  // 1 => int32 data
}

__device__ __forceinline__ int load_idx(const void* ei, int flag, size_t pos) {
    return flag ? ((const int*)ei)[pos] : (int)((const long long*)ei)[pos];
}

// ---------- tiny zero of ghist (replaces rocclr fillBuffer dispatch) ----------
__global__ __launch_bounds__(256) void zeroA_kernel(int* __restrict__ ghist) {
    int t = threadIdx.x;
#pragma unroll
    for (int k = 0; k < NB / 256; ++k) ghist[t + k * 256] = 0;
}

// ---------- mega1: gemm1 (MFMA f16) blocks first, then histA blocks ----------
__global__ __launch_bounds__(256) void mega1_kernel(const float* __restrict__ X,
                                                    const float* __restrict__ W,
                                                    u32* __restrict__ Y,
                                                    const void* __restrict__ ei,
                                                    int* __restrict__ ghist) {
    __shared__ float Wsh[NFEAT * NHID];  // 32 KB (hist path reuses as int cnt[NB])
    int t = threadIdx.x;
    if (blockIdx.x < GEMM_BLOCKS) {
        for (int i = t; i < NFEAT * NHID; i += 256) Wsh[i] = W[i];
        __syncthreads();
        int wid = t >> 6;
        int lane = t & 63;
        int r = lane & 15, g = lane >> 4;
        int m0 = (blockIdx.x * 4 + wid) * 16;
        if (m0 >= N_NODES) return;

        f16x8 af[4][4];  // [ntile][ktile]
#pragma unroll
        for (int nt = 0; nt < 4; ++nt)
#pragma unroll
            for (int kt = 0; kt < 4; ++kt)
#pragma unroll
                for (int j = 0; j < 8; ++j)
                    af[nt][kt][j] = (_Float16)Wsh[(kt * 32 + g * 8 + j) * NHID + nt * 16 + r];

        const float* xr = X + (size_t)(m0 + r) * NFEAT + g * 8;
        f16x8 bfr[4];
#pragma unroll
        for (int kt = 0; kt < 4; ++kt) {
            float4 v0 = *(const float4*)(xr + kt * 32);
            float4 v1 = *(const float4*)(xr + kt * 32 + 4);
            bfr[kt][0] = (_Float16)v0.x; bfr[kt][1] = (_Float16)v0.y;
            bfr[kt][2] = (_Float16)v0.z; bfr[kt][3] = (_Float16)v0.w;
            bfr[kt][4] = (_Float16)v1.x; bfr[kt][5] = (_Float16)v1.y;
            bfr[kt][6] = (_Float16)v1.z; bfr[kt][7] = (_Float16)v1.w;
        }

        u32* yr = Y + (size_t)(m0 + r) * (NHID / 2);
#pragma unroll
        for (int nt = 0; nt < 4; ++nt) {
            f32x4 acc = {0.f, 0.f, 0.f, 0.f};
#pragma unroll
            for (int kt = 0; kt < 4; ++kt)
                acc = __builtin_amdgcn_mfma_f32_16x16x32_f16(af[nt][kt], bfr[kt], acc, 0, 0, 0);
            uint2 o;
            o.x = pack_h16(acc[0], acc[1]);
            o.y = pack_h16(acc[2], acc[3]);
            *(uint2*)(yr + nt * 8 + g * 2) = o;
        }
    } else {
        int* cnt = (int*)Wsh;
        int bid = blockIdx.x - GEMM_BLOCKS;
#pragma unroll
        for (int k = 0; k < NB / 256; ++k) cnt[t + k * 256] = 0;
        __syncthreads();
        int f = detect_i32(ei);
        int base = bid * 256 * HIST_EPT;
#pragma unroll
        for (int k = 0; k < HIST_EPT; ++k) {
            int e = base + k * 256 + t;
            if (e < N_EDGES) {
                int d = load_idx(ei, f, (size_t)N_EDGES + e);
                atomicAdd(&cnt[d / NPB], 1);
            }
        }
        __syncthreads();
#pragma unroll
        for (int k = 0; k < NB / 256; ++k)
            if (cnt[t + k * 256] > 0) atomicAdd(&ghist[t + k * 256], cnt[t + k * 256]);
    }
}

// single-block scan of NB bucket counts -> bstart (exclusive) + gcursor
__global__ __launch_bounds__(1024) void scanA_kernel(const int* __restrict__ ghist,
                                                     int* __restrict__ bstart,
                                                     int* __restrict__ gcursor) {
    __shared__ int lds[NB];
    int t = threadIdx.x;
    int own = ghist[t];
    lds[t] = own;
    __syncthreads();
    for (int off = 1; off < NB; off <<= 1) {
        int v = (t >= off) ? lds[t - off] : 0;
        __syncthreads();
        lds[t] += v;
        __syncthreads();
    }
    int excl = lds[t] - own;
    bstart[t] = excl;
    if (t == NB - 1) bstart[NB] = lds[NB - 1];
    gcursor[t] = excl;
}

// block-privatized bin scatter: {src | dstl<<20, w} into bucket-contiguous ebuf
__global__ __launch_bounds__(256) void fillA_kernel(const void* __restrict__ ei,
                                                    const float* __restrict__ ew,
                                                    int* __restrict__ gcursor,
                                                    int2* __restrict__ ebuf) {
    __shared__ int cnt[NB];
    __shared__ int base[NB];
    int t = threadIdx.x;
#pragma unroll
    for (int k = 0; k < NB / 256; ++k) cnt[t + k * 256] = 0;
    __syncthreads();
    int f = detect_i32(ei);
    int eb = blockIdx.x * 256 * FILL_EPT;
    int src[FILL_EPT], bin[FILL_EPT], rank[FILL_EPT];
    float w[FILL_EPT];
#pragma unroll
    for (int k = 0; k < FILL_EPT; ++k) {
        int e = eb + k * 256 + t;
        bin[k] = -1;
        if (e < N_EDGES) {
            int s = load_idx(ei, f, (size_t)e);
            int d = load_idx(ei, f, (size_t)N_EDGES + e);
            int b = d / NPB;
            src[k] = s | ((d - b * NPB) << 20);
            w[k] = ew[e];
            bin[k] = b;
            rank[k] = atomicAdd(&cnt[b], 1);
        }
    }
    __syncthreads();
#pragma unroll
    for (int k = 0; k < NB / 256; ++k)
        if (cnt[t + k * 256] > 0) base[t + k * 256] = atomicAdd(&gcursor[t + k * 256], cnt[t + k * 256]);
    __syncthreads();
#pragma unroll
    for (int k = 0; k < FILL_EPT; ++k) {
        if (bin[k] >= 0) {
            int pos = base[bin[k]] + rank[k];
            ebuf[pos] = make_int2(src[k], __float_as_int(w[k]));
        }
    }
}

// per-bucket counting sort -> exact CSR (ebuf2) + row_ptr
__global__ __launch_bounds__(256) void sortB_kernel(const int2* __restrict__ ebuf,
                                                    const int* __restrict__ bstart,
                                                    int2* __restrict__ ebuf2,
                                                    int* __restrict__ row_ptr) {
    __shared__ int cnt[NPB];
    __shared__ int sc[256];
    __shared__ int cur[NPB];
    int t = threadIdx.x, b = blockIdx.x;
    if (t < NPB) cnt[t] = 0;
    __syncthreads();
    int start = bstart[b], end = bstart[b + 1];
    for (int i = start + t; i < end; i += 256) {
        int dl = ((u32)ebuf[i].x) >> 20;
        atomicAdd(&cnt[dl], 1);
    }
    __syncthreads();
    int own = (t < NPB) ? cnt[t] : 0;
    sc[t] = own;
    __syncthreads();
    for (int off = 1; off < 256; off <<= 1) {
        int v = (t >= off) ? sc[t - off] : 0;
        __syncthreads();
        sc[t] += v;
        __syncthreads();
    }
    int excl = sc[t] - own;
    if (t < NPB) {
        cur[t] = excl;
        int node = b * NPB + t;
        if (node < N_NODES) row_ptr[node] = start + excl;
    }
    if (b == 0 && t == 0) row_ptr[N_NODES] = N_EDGES;
    __syncthreads();
    for (int i = start + t; i < end; i += 256) {
        int2 p = ebuf[i];
        int dl = ((u32)p.x) >> 20;
        int pos = start + atomicAdd(&cur[dl], 1);
        ebuf2[pos] = make_int2(p.x & 0xFFFFF, p.y);
    }
}

// ---------- gemm2 via MFMA f16: D = W2^T x h^T; B-frags load packed-f16 h ----------
__global__ __launch_bounds__(256) void gemm2_kernel(const u32* __restrict__ Hb,
                                                    const float* __restrict__ W,
                                                    u32* __restrict__ Y) {
    __shared__ float Wsh[NHID * NCLASS];  // 4 KB
    int t = threadIdx.x;
    for (int i = t; i < NHID * NCLASS; i += 256) Wsh[i] = W[i];
    __syncthreads();
    int wid = t >> 6;
    int lane = t & 63;
    int r = lane & 15, g = lane >> 4;
    int m0 = (blockIdx.x * 4 + wid) * 16;
    if (m0 >= N_NODES) return;

    f16x8 af[2];
#pragma unroll
    for (int kt = 0; kt < 2; ++kt)
#pragma unroll
        for (int j = 0; j < 8; ++j)
            af[kt][j] = (_Float16)Wsh[(kt * 32 + g * 8 + j) * NCLASS + r];

    const u32* hr = Hb + (size_t)(m0 + r) * (NHID / 2) + g * 4;
    union { uint4 u; f16x8 h; } b0, b1;
    b0.u = *(const uint4*)(hr + 0);
    b1.u = *(const uint4*)(hr + 16);

    f32x4 acc = {0.f, 0.f, 0.f, 0.f};
    acc = __builtin_amdgcn_mfma_f32_16x16x32_f16(af[0], b0.h, acc, 0, 0, 0);
    acc = __builtin_amdgcn_mfma_f32_16x16x32_f16(af[1], b1.h, acc, 0, 0, 0);

    u32* yr = Y + (size_t)(m0 + r) * (NCLASS / 2);
    uint2 o;
    o.x = pack_h16(acc[0], acc[1]);
    o.y = pack_h16(acc[2], acc[3]);
    *(uint2*)(yr + g * 2) = o;
}

// ---------- CSR aggregation with packed-f16 math + LDS-staged edge records ----------
// Each block covers exactly 4 nodes whose CSR edge ranges are contiguous; the
// block cooperatively stages its ep slice (~64 edges) into LDS so the per-edge
// dependent chain is ds_read -> gather instead of global -> global.
// Layer 1: one wave per node; lane = sub*8+p (8 subs); lane gathers uint4;
// 2-deep masked unroll -> 16 gathers in flight; butterfly masks 8,16,32.
__global__ __launch_bounds__(256) void agg1_kernel(const u32* __restrict__ xwb,
                                                   const int* __restrict__ row_ptr,
                                                   const int2* __restrict__ ep,
                                                   u32* __restrict__ hb) {
    __shared__ int2 eps[EPS_CAP];
    __shared__ int shse[2];
    int tt = threadIdx.x;
    int blk0 = blockIdx.x * 4;
    if (tt == 0) {
        shse[0] = row_ptr[min(blk0, N_NODES)];
        shse[1] = row_ptr[min(blk0 + 4, N_NODES)];
    }
    __syncthreads();
    int bs = shse[0], be = shse[1];
    bool staged = (be - bs) <= EPS_CAP;
    if (staged) {
        for (int i = bs + tt; i < be; i += 256) eps[i - bs] = ep[i];
    }
    __syncthreads();
    int node = blk0 + (tt >> 6);
    int lane = tt & 63;
    int p = lane & 7;
    int sub = lane >> 3;
    if (node >= N_NODES) return;
    int start = row_ptr[node], end = row_ptr[node + 1];
    int last = end - 1;
    __half2 a0 = u2h2(0), a1 = u2h2(0), a2 = u2h2(0), a3 = u2h2(0);
    __half2 b0 = u2h2(0), b1 = u2h2(0), b2 = u2h2(0), b3 = u2h2(0);
    for (int i = start + sub; i < end; i += 16) {
        int j1 = min(i + 8, last);
        int2 p0 = staged ? eps[i - bs] : ep[i];
        int2 p1 = staged ? eps[j1 - bs] : ep[j1];
        uint4 u0 = *(const uint4*)(xwb + (size_t)p0.x * 32 + 4 * p);
        uint4 u1 = *(const uint4*)(xwb + (size_t)p1.x * 32 + 4 * p);
        float w0f = __int_as_float(p0.y);
        float w1f = (i + 8 < end) ? __int_as_float(p1.y) : 0.f;
        __half2 w0 = __half2half2(__float2half(w0f));
        __half2 w1 = __half2half2(__float2half(w1f));
        a0 = __hfma2(u2h2(u0.x), w0, a0); a1 = __hfma2(u2h2(u0.y), w0, a1);
        a2 = __hfma2(u2h2(u0.z), w0, a2); a3 = __hfma2(u2h2(u0.w), w0, a3);
        b0 = __hfma2(u2h2(u1.x), w1, b0); b1 = __hfma2(u2h2(u1.y), w1, b1);
        b2 = __hfma2(u2h2(u1.z), w1, b2); b3 = __hfma2(u2h2(u1.w), w1, b3);
    }
    a0 = __hadd2(a0, b0); a1 = __hadd2(a1, b1);
    a2 = __hadd2(a2, b2); a3 = __hadd2(a3, b3);
#pragma unroll
    for (int m = 8; m <= 32; m <<= 1) {
        a0 = __hadd2(a0, u2h2((u32)__shfl_xor((int)h22u(a0), m, 64)));
        a1 = __hadd2(a1, u2h2((u32)__shfl_xor((int)h22u(a1), m, 64)));
        a2 = __hadd2(a2, u2h2((u32)__shfl_xor((int)h22u(a2), m, 64)));
        a3 = __hadd2(a3, u2h2((u32)__shfl_xor((int)h22u(a3), m, 64)));
    }
    if (sub == 0) {
        float2 f0 = __half22float2(a0);
        float2 f1 = __half22float2(a1);
        float2 f2 = __half22float2(a2);
        float2 f3 = __half22float2(a3);
        uint4 o;
        o.x = pack_h16(fmaxf(f0.x, 0.f), fmaxf(f0.y, 0.f));
        o.y = pack_h16(fmaxf(f1.x, 0.f), fmaxf(f1.y, 0.f));
        o.z = pack_h16(fmaxf(f2.x, 0.f), fmaxf(f2.y, 0.f));
        o.w = pack_h16(fmaxf(f3.x, 0.f), fmaxf(f3.y, 0.f));
        *(uint4*)(hb + (size_t)node * 32 + 4 * p) = o;
    }
}

// Layer 2: same LDS staging; one wave per node; lane = sub*2+p (32 subs);
// lane gathers uint4 (8 classes); deg~16 completes in one un-masked pass.
__global__ __launch_bounds__(256) void agg2_kernel(const u32* __restrict__ hwb,
                                                   const int* __restrict__ row_ptr,
                                                   const int2* __restrict__ ep,
                                                   float* __restrict__ out) {
    __shared__ int2 eps[EPS_CAP];
    __shared__ int shse[2];
    int tt = threadIdx.x;
    int blk0 = blockIdx.x * 4;
    if (tt == 0) {
        shse[0] = row_ptr[min(blk0, N_NODES)];
        shse[1] = row_ptr[min(blk0 + 4, N_NODES)];
    }
    __syncthreads();
    int bs = shse[0], be = shse[1];
    bool staged = (be - bs) <= EPS_CAP;
    if (staged) {
        for (int i = bs + tt; i < be; i += 256) eps[i - bs] = ep[i];
    }
    __syncthreads();
    int node = blk0 + (tt >> 6);
    int lane = tt & 63;
    int p = lane & 1;
    int sub = lane >> 1;
    if (node >= N_NODES) return;
    int start = row_ptr[node], end = row_ptr[node + 1];
    __half2 a0 = u2h2(0), a1 = u2h2(0), a2 = u2h2(0), a3 = u2h2(0);
    for (int i = start + sub; i < end; i += 32) {
        int2 pr = staged ? eps[i - bs] : ep[i];
        uint4 u = *(const uint4*)(hwb + (size_t)pr.x * 8 + 4 * p);
        __half2 w = __half2half2(__float2half(__int_as_float(pr.y)));
        a0 = __hfma2(u2h2(u.x), w, a0); a1 = __hfma2(u2h2(u.y), w, a1);
        a2 = __hfma2(u2h2(u.z), w, a2); a3 = __hfma2(u2h2(u.w), w, a3);
    }
#pragma unroll
    for (int m = 2; m <= 32; m <<= 1) {
        a0 = __hadd2(a0, u2h2((u32)__shfl_xor((int)h22u(a0), m, 64)));
        a1 = __hadd2(a1, u2h2((u32)__shfl_xor((int)h22u(a1), m, 64)));
        a2 = __hadd2(a2, u2h2((u32)__shfl_xor((int)h22u(a2), m, 64)));
        a3 = __hadd2(a3, u2h2((u32)__shfl_xor((int)h22u(a3), m, 64)));
    }
    if (sub == 0) {
        float2 f0 = __half22float2(a0);
        float2 f1 = __half22float2(a1);
        float2 f2 = __half22float2(a2);
        float2 f3 = __half22float2(a3);
        float* op = out + (size_t)node * NCLASS + 8 * p;
        *(float4*)(op + 0) = make_float4(f0.x, f0.y, f1.x, f1.y);
        *(float4*)(op + 4) = make_float4(f2.x, f2.y, f3.x, f3.y);
    }
}

extern "C" void kernel_launch(void* const* d_in, const int* in_sizes, int n_in,
                              void* d_out, int out_size, void* d_ws, size_t ws_size,
                              hipStream_t stream) {
    const float* x  = (const float*)d_in[0];
    const void*  ei = d_in[1];
    const float* ew = (const float*)d_in[2];
    const float* W1 = (const float*)d_in[3];
    const float* W2 = (const float*)d_in[4];
    float* out = (float*)d_out;

    char* ws = (char*)d_ws;
    size_t off = 0;
    auto take = [&](size_t bytes) {
        char* p = ws + off;
        off += (bytes + 511) & ~(size_t)511;
        return p;
    };
    int*   ghist   = (int*)take(NB * 4);
    int*   bstart  = (int*)take((NB + 1) * 4);
    int*   gcursor = (int*)take(NB * 4);
    int*   row_ptr = (int*)take((size_t)(N_NODES + 1) * 4);
    int2*  ebuf    = (int2*)take((size_t)N_EDGES * 8);
    int2*  ebuf2   = (int2*)take((size_t)N_EDGES * 8);
    u32*   xwb     = (u32*)take((size_t)N_NODES * (NHID / 2) * 4);   // f16 packed
    u32*   hb      = (u32*)take((size_t)N_NODES * (NHID / 2) * 4);   // f16 packed
    u32*   hwb     = (u32*)take((size_t)N_NODES * (NCLASS / 2) * 4); // f16 packed

    zeroA_kernel<<<1, 256, 0, stream>>>(ghist);
    mega1_kernel<<<GEMM_BLOCKS + HIST_BLOCKS, 256, 0, stream>>>(x, W1, xwb, ei, ghist);
    scanA_kernel<<<1, NB, 0, stream>>>(ghist, bstart, gcursor);
    fillA_kernel<<<FILL_BLOCKS, 256, 0, stream>>>(ei, ew, gcursor, ebuf);
    sortB_kernel<<<NB, 256, 0, stream>>>(ebuf, bstart, ebuf2, row_ptr);

    agg1_kernel<<<(N_NODES + 3) / 4, 256, 0, stream>>>(xwb, row_ptr, ebuf2, hb);
    gemm2_kernel<<<GEMM_BLOCKS, 256, 0, stream>>>(hb, W2, hwb);
    agg2_kernel<<<(N_NODES + 3) / 4, 256, 0, stream>>>(hwb, row_ptr, ebuf2, out);
}

// Round 17
// 144.370 us; speedup vs baseline: 1.0574x; 1.0574x over previous
//
#include <hip/hip_runtime.h>
#include <hip/hip_fp16.h>

#define N_NODES 100000
#define N_EDGES 1600000
#define NFEAT 128
#define NHID 64
#define NCLASS 16

#define NPB 98                     // dst-nodes per bucket
#define NB 1024                    // ceil(100000 / 98) = 1021 -> pad to 1024
#define HIST_EPT 16
#define HIST_BLOCKS ((N_EDGES + 256 * HIST_EPT - 1) / (256 * HIST_EPT))  // 391
#define FILL_EPT 16
#define FILL_BLOCKS ((N_EDGES + 256 * FILL_EPT - 1) / (256 * FILL_EPT))  // 391
#define NTILES ((N_NODES + 15) / 16)            // 6250
#define GEMM_BLOCKS ((NTILES + 3) / 4)          // 1563
#define EPS_CAP 1024               // LDS edge-stage capacity (4-node range; avg 64)

typedef unsigned int u32;
typedef __attribute__((ext_vector_type(8))) _Float16 f16x8;
typedef __attribute__((ext_vector_type(4))) float f32x4;

__device__ __forceinline__ __half2 u2h2(u32 u) { __half2 h; __builtin_memcpy(&h, &u, 4); return h; }
__device__ __forceinline__ u32 h22u(__half2 h) { u32 u; __builtin_memcpy(&u, &h, 4); return u; }
__device__ __forceinline__ u32 pack_h16(float a, float b) { return h22u(__floats2half2_rn(a, b)); }

// per-block edge-index dtype detection: odd u32 of first 64 int64 slots are all
// zero iff data is int64 (node ids < 2^31).
__device__ __forceinline__ int detect_i32(const void* ei) {
    u32 v = ((const u32*)ei)[2 * (threadIdx.x & 63) + 1];
    return (__ballot(v != 0) != 0ULL) ? 1 : 0;  // 1 => int32 data
}

__device__ __forceinline__ int load_idx(const void* ei, int flag, size_t pos) {
    return flag ? ((const int*)ei)[pos] : (int)((const long long*)ei)[pos];
}

// ---------- tiny zero of ghist (replaces rocclr fillBuffer dispatch) ----------
__global__ __launch_bounds__(256) void zeroA_kernel(int* __restrict__ ghist) {
    int t = threadIdx.x;
#pragma unroll
    for (int k = 0; k < NB / 256; ++k) ghist[t + k * 256] = 0;
}

// ---------- mega1: gemm1 (MFMA f16) blocks first, then histA blocks ----------
__global__ __launch_bounds__(256) void mega1_kernel(const float* __restrict__ X,
                                                    const float* __restrict__ W,
                                                    u32* __restrict__ Y,
                                                    const void* __restrict__ ei,
                                                    int* __restrict__ ghist) {
    __shared__ float Wsh[NFEAT * NHID];  // 32 KB (hist path reuses as int cnt[NB])
    int t = threadIdx.x;
    if (blockIdx.x < GEMM_BLOCKS) {
        for (int i = t; i < NFEAT * NHID; i += 256) Wsh[i] = W[i];
        __syncthreads();
        int wid = t >> 6;
        int lane = t & 63;
        int r = lane & 15, g = lane >> 4;
        int m0 = (blockIdx.x * 4 + wid) * 16;
        if (m0 >= N_NODES) return;

        f16x8 af[4][4];  // [ntile][ktile]
#pragma unroll
        for (int nt = 0; nt < 4; ++nt)
#pragma unroll
            for (int kt = 0; kt < 4; ++kt)
#pragma unroll
                for (int j = 0; j < 8; ++j)
                    af[nt][kt][j] = (_Float16)Wsh[(kt * 32 + g * 8 + j) * NHID + nt * 16 + r];

        const float* xr = X + (size_t)(m0 + r) * NFEAT + g * 8;
        f16x8 bfr[4];
#pragma unroll
        for (int kt = 0; kt < 4; ++kt) {
            float4 v0 = *(const float4*)(xr + kt * 32);
            float4 v1 = *(const float4*)(xr + kt * 32 + 4);
            bfr[kt][0] = (_Float16)v0.x; bfr[kt][1] = (_Float16)v0.y;
            bfr[kt][2] = (_Float16)v0.z; bfr[kt][3] = (_Float16)v0.w;
            bfr[kt][4] = (_Float16)v1.x; bfr[kt][5] = (_Float16)v1.y;
            bfr[kt][6] = (_Float16)v1.z; bfr[kt][7] = (_Float16)v1.w;
        }

        u32* yr = Y + (size_t)(m0 + r) * (NHID / 2);
#pragma unroll
        for (int nt = 0; nt < 4; ++nt) {
            f32x4 acc = {0.f, 0.f, 0.f, 0.f};
#pragma unroll
            for (int kt = 0; kt < 4; ++kt)
                acc = __builtin_amdgcn_mfma_f32_16x16x32_f16(af[nt][kt], bfr[kt], acc, 0, 0, 0);
            uint2 o;
            o.x = pack_h16(acc[0], acc[1]);
            o.y = pack_h16(acc[2], acc[3]);
            *(uint2*)(yr + nt * 8 + g * 2) = o;
        }
    } else {
        int* cnt = (int*)Wsh;
        int bid = blockIdx.x - GEMM_BLOCKS;
#pragma unroll
        for (int k = 0; k < NB / 256; ++k) cnt[t + k * 256] = 0;
        __syncthreads();
        int f = detect_i32(ei);
        int base = bid * 256 * HIST_EPT;
#pragma unroll
        for (int k = 0; k < HIST_EPT; ++k) {
            int e = base + k * 256 + t;
            if (e < N_EDGES) {
                int d = load_idx(ei, f, (size_t)N_EDGES + e);
                atomicAdd(&cnt[d / NPB], 1);
            }
        }
        __syncthreads();
#pragma unroll
        for (int k = 0; k < NB / 256; ++k)
            if (cnt[t + k * 256] > 0) atomicAdd(&ghist[t + k * 256], cnt[t + k * 256]);
    }
}

// single-block scan of NB bucket counts -> bstart (exclusive) + gcursor
__global__ __launch_bounds__(1024) void scanA_kernel(const int* __restrict__ ghist,
                                                     int* __restrict__ bstart,
                                                     int* __restrict__ gcursor) {
    __shared__ int lds[NB];
    int t = threadIdx.x;
    int own = ghist[t];
    lds[t] = own;
    __syncthreads();
    for (int off = 1; off < NB; off <<= 1) {
        int v = (t >= off) ? lds[t - off] : 0;
        __syncthreads();
        lds[t] += v;
        __syncthreads();
    }
    int excl = lds[t] - own;
    bstart[t] = excl;
    if (t == NB - 1) bstart[NB] = lds[NB - 1];
    gcursor[t] = excl;
}

// block-privatized bin scatter: {src | dstl<<20, w} into bucket-contiguous ebuf
__global__ __launch_bounds__(256) void fillA_kernel(const void* __restrict__ ei,
                                                    const float* __restrict__ ew,
                                                    int* __restrict__ gcursor,
                                                    int2* __restrict__ ebuf) {
    __shared__ int cnt[NB];
    __shared__ int base[NB];
    int t = threadIdx.x;
#pragma unroll
    for (int k = 0; k < NB / 256; ++k) cnt[t + k * 256] = 0;
    __syncthreads();
    int f = detect_i32(ei);
    int eb = blockIdx.x * 256 * FILL_EPT;
    int src[FILL_EPT], bin[FILL_EPT], rank[FILL_EPT];
    float w[FILL_EPT];
#pragma unroll
    for (int k = 0; k < FILL_EPT; ++k) {
        int e = eb + k * 256 + t;
        bin[k] = -1;
        if (e < N_EDGES) {
            int s = load_idx(ei, f, (size_t)e);
            int d = load_idx(ei, f, (size_t)N_EDGES + e);
            int b = d / NPB;
            src[k] = s | ((d - b * NPB) << 20);
            w[k] = ew[e];
            bin[k] = b;
            rank[k] = atomicAdd(&cnt[b], 1);
        }
    }
    __syncthreads();
#pragma unroll
    for (int k = 0; k < NB / 256; ++k)
        if (cnt[t + k * 256] > 0) base[t + k * 256] = atomicAdd(&gcursor[t + k * 256], cnt[t + k * 256]);
    __syncthreads();
#pragma unroll
    for (int k = 0; k < FILL_EPT; ++k) {
        if (bin[k] >= 0) {
            int pos = base[bin[k]] + rank[k];
            ebuf[pos] = make_int2(src[k], __float_as_int(w[k]));
        }
    }
}

// per-bucket counting sort -> exact CSR (ebuf2) + row_ptr
__global__ __launch_bounds__(256) void sortB_kernel(const int2* __restrict__ ebuf,
                                                    const int* __restrict__ bstart,
                                                    int2* __restrict__ ebuf2,
                                                    int* __restrict__ row_ptr) {
    __shared__ int cnt[NPB];
    __shared__ int sc[256];
    __shared__ int cur[NPB];
    int t = threadIdx.x, b = blockIdx.x;
    if (t < NPB) cnt[t] = 0;
    __syncthreads();
    int start = bstart[b], end = bstart[b + 1];
    for (int i = start + t; i < end; i += 256) {
        int dl = ((u32)ebuf[i].x) >> 20;
        atomicAdd(&cnt[dl], 1);
    }
    __syncthreads();
    int own = (t < NPB) ? cnt[t] : 0;
    sc[t] = own;
    __syncthreads();
    for (int off = 1; off < 256; off <<= 1) {
        int v = (t >= off) ? sc[t - off] : 0;
        __syncthreads();
        sc[t] += v;
        __syncthreads();
    }
    int excl = sc[t] - own;
    if (t < NPB) {
        cur[t] = excl;
        int node = b * NPB + t;
        if (node < N_NODES) row_ptr[node] = start + excl;
    }
    if (b == 0 && t == 0) row_ptr[N_NODES] = N_EDGES;
    __syncthreads();
    for (int i = start + t; i < end; i += 256) {
        int2 p = ebuf[i];
        int dl = ((u32)p.x) >> 20;
        int pos = start + atomicAdd(&cur[dl], 1);
        ebuf2[pos] = make_int2(p.x & 0xFFFFF, p.y);
    }
}

// ---------- gemm2 via MFMA f16: D = W2^T x h^T; B-frags load packed-f16 h ----------
__global__ __launch_bounds__(256) void gemm2_kernel(const u32* __restrict__ Hb,
                                                    const float* __restrict__ W,
                                                    u32* __restrict__ Y) {
    __shared__ float Wsh[NHID * NCLASS];  // 4 KB
    int t = threadIdx.x;
    for (int i = t; i < NHID * NCLASS; i += 256) Wsh[i] = W[i];
    __syncthreads();
    int wid = t >> 6;
    int lane = t & 63;
    int r = lane & 15, g = lane >> 4;
    int m0 = (blockIdx.x * 4 + wid) * 16;
    if (m0 >= N_NODES) return;

    f16x8 af[2];
#pragma unroll
    for (int kt = 0; kt < 2; ++kt)
#pragma unroll
        for (int j = 0; j < 8; ++j)
            af[kt][j] = (_Float16)Wsh[(kt * 32 + g * 8 + j) * NCLASS + r];

    const u32* hr = Hb + (size_t)(m0 + r) * (NHID / 2) + g * 4;
    union { uint4 u; f16x8 h; } b0, b1;
    b0.u = *(const uint4*)(hr + 0);
    b1.u = *(const uint4*)(hr + 16);

    f32x4 acc = {0.f, 0.f, 0.f, 0.f};
    acc = __builtin_amdgcn_mfma_f32_16x16x32_f16(af[0], b0.h, acc, 0, 0, 0);
    acc = __builtin_amdgcn_mfma_f32_16x16x32_f16(af[1], b1.h, acc, 0, 0, 0);

    u32* yr = Y + (size_t)(m0 + r) * (NCLASS / 2);
    uint2 o;
    o.x = pack_h16(acc[0], acc[1]);
    o.y = pack_h16(acc[2], acc[3]);
    *(uint2*)(yr + g * 2) = o;
}

// ---------- agg1: LDS-staged edge records (HBM-class gather hidden) ----------
// Each block covers exactly 4 nodes with contiguous CSR ranges; block stages
// its ep slice (~64 edges) into LDS; per-edge chain becomes ds_read -> gather.
// One wave per node; lane = sub*8+p (8 subs); lane gathers uint4 (8 feats);
// 2-deep masked unroll -> 16 gathers in flight; butterfly masks 8,16,32.
__global__ __launch_bounds__(256) void agg1_kernel(const u32* __restrict__ xwb,
                                                   const int* __restrict__ row_ptr,
                                                   const int2* __restrict__ ep,
                                                   u32* __restrict__ hb) {
    __shared__ int2 eps[EPS_CAP];
    __shared__ int shse[2];
    int tt = threadIdx.x;
    int blk0 = blockIdx.x * 4;
    if (tt == 0) {
        shse[0] = row_ptr[min(blk0, N_NODES)];
        shse[1] = row_ptr[min(blk0 + 4, N_NODES)];
    }
    __syncthreads();
    int bs = shse[0], be = shse[1];
    bool staged = (be - bs) <= EPS_CAP;
    if (staged) {
        for (int i = bs + tt; i < be; i += 256) eps[i - bs] = ep[i];
    }
    __syncthreads();
    int node = blk0 + (tt >> 6);
    int lane = tt & 63;
    int p = lane & 7;
    int sub = lane >> 3;
    if (node >= N_NODES) return;
    int start = row_ptr[node], end = row_ptr[node + 1];
    int last = end - 1;
    __half2 a0 = u2h2(0), a1 = u2h2(0), a2 = u2h2(0), a3 = u2h2(0);
    __half2 b0 = u2h2(0), b1 = u2h2(0), b2 = u2h2(0), b3 = u2h2(0);
    for (int i = start + sub; i < end; i += 16) {
        int j1 = min(i + 8, last);
        int2 p0 = staged ? eps[i - bs] : ep[i];
        int2 p1 = staged ? eps[j1 - bs] : ep[j1];
        uint4 u0 = *(const uint4*)(xwb + (size_t)p0.x * 32 + 4 * p);
        uint4 u1 = *(const uint4*)(xwb + (size_t)p1.x * 32 + 4 * p);
        float w0f = __int_as_float(p0.y);
        float w1f = (i + 8 < end) ? __int_as_float(p1.y) : 0.f;
        __half2 w0 = __half2half2(__float2half(w0f));
        __half2 w1 = __half2half2(__float2half(w1f));
        a0 = __hfma2(u2h2(u0.x), w0, a0); a1 = __hfma2(u2h2(u0.y), w0, a1);
        a2 = __hfma2(u2h2(u0.z), w0, a2); a3 = __hfma2(u2h2(u0.w), w0, a3);
        b0 = __hfma2(u2h2(u1.x), w1, b0); b1 = __hfma2(u2h2(u1.y), w1, b1);
        b2 = __hfma2(u2h2(u1.z), w1, b2); b3 = __hfma2(u2h2(u1.w), w1, b3);
    }
    a0 = __hadd2(a0, b0); a1 = __hadd2(a1, b1);
    a2 = __hadd2(a2, b2); a3 = __hadd2(a3, b3);
#pragma unroll
    for (int m = 8; m <= 32; m <<= 1) {
        a0 = __hadd2(a0, u2h2((u32)__shfl_xor((int)h22u(a0), m, 64)));
        a1 = __hadd2(a1, u2h2((u32)__shfl_xor((int)h22u(a1), m, 64)));
        a2 = __hadd2(a2, u2h2((u32)__shfl_xor((int)h22u(a2), m, 64)));
        a3 = __hadd2(a3, u2h2((u32)__shfl_xor((int)h22u(a3), m, 64)));
    }
    if (sub == 0) {
        float2 f0 = __half22float2(a0);
        float2 f1 = __half22float2(a1);
        float2 f2 = __half22float2(a2);
        float2 f3 = __half22float2(a3);
        uint4 o;
        o.x = pack_h16(fmaxf(f0.x, 0.f), fmaxf(f0.y, 0.f));
        o.y = pack_h16(fmaxf(f1.x, 0.f), fmaxf(f1.y, 0.f));
        o.z = pack_h16(fmaxf(f2.x, 0.f), fmaxf(f2.y, 0.f));
        o.w = pack_h16(fmaxf(f3.x, 0.f), fmaxf(f3.y, 0.f));
        *(uint4*)(hb + (size_t)node * 32 + 4 * p) = o;
    }
}

// ---------- agg2: UNstaged (gathers are L2-resident; staging is overhead) ----------
// One wave per node; lane = sub*2+p (32 subs); lane gathers uint4 (8 classes);
// deg~16 completes in one un-masked pass; butterfly masks 2..32; fp32 out.
__global__ __launch_bounds__(256) void agg2_kernel(const u32* __restrict__ hwb,
                                                   const int* __restrict__ row_ptr,
                                                   const int2* __restrict__ ep,
                                                   float* __restrict__ out) {
    int t = blockIdx.x * 256 + threadIdx.x;
    int node = t >> 6;
    int lane = t & 63;
    int p = lane & 1;
    int sub = lane >> 1;
    if (node >= N_NODES) return;
    int start = row_ptr[node], end = row_ptr[node + 1];
    __half2 a0 = u2h2(0), a1 = u2h2(0), a2 = u2h2(0), a3 = u2h2(0);
    for (int i = start + sub; i < end; i += 32) {
        int2 pr = ep[i];
        uint4 u = *(const uint4*)(hwb + (size_t)pr.x * 8 + 4 * p);
        __half2 w = __half2half2(__float2half(__int_as_float(pr.y)));
        a0 = __hfma2(u2h2(u.x), w, a0); a1 = __hfma2(u2h2(u.y), w, a1);
        a2 = __hfma2(u2h2(u.z), w, a2); a3 = __hfma2(u2h2(u.w), w, a3);
    }
#pragma unroll
    for (int m = 2; m <= 32; m <<= 1) {
        a0 = __hadd2(a0, u2h2((u32)__shfl_xor((int)h22u(a0), m, 64)));
        a1 = __hadd2(a1, u2h2((u32)__shfl_xor((int)h22u(a1), m, 64)));
        a2 = __hadd2(a2, u2h2((u32)__shfl_xor((int)h22u(a2), m, 64)));
        a3 = __hadd2(a3, u2h2((u32)__shfl_xor((int)h22u(a3), m, 64)));
    }
    if (sub == 0) {
        float2 f0 = __half22float2(a0);
        float2 f1 = __half22float2(a1);
        float2 f2 = __half22float2(a2);
        float2 f3 = __half22float2(a3);
        float* op = out + (size_t)node * NCLASS + 8 * p;
        *(float4*)(op + 0) = make_float4(f0.x, f0.y, f1.x, f1.y);
        *(float4*)(op + 4) = make_float4(f2.x, f2.y, f3.x, f3.y);
    }
}

extern "C" void kernel_launch(void* const* d_in, const int* in_sizes, int n_in,
                              void* d_out, int out_size, void* d_ws, size_t ws_size,
                              hipStream_t stream) {
    const float* x  = (const float*)d_in[0];
    const void*  ei = d_in[1];
    const float* ew = (const float*)d_in[2];
    const float* W1 = (const float*)d_in[3];
    const float* W2 = (const float*)d_in[4];
    float* out = (float*)d_out;

    char* ws = (char*)d_ws;
    size_t off = 0;
    auto take = [&](size_t bytes) {
        char* p = ws + off;
        off += (bytes + 511) & ~(size_t)511;
        return p;
    };
    int*   ghist   = (int*)take(NB * 4);
    int*   bstart  = (int*)take((NB + 1) * 4);
    int*   gcursor = (int*)take(NB * 4);
    int*   row_ptr = (int*)take((size_t)(N_NODES + 1) * 4);
    int2*  ebuf    = (int2*)take((size_t)N_EDGES * 8);
    int2*  ebuf2   = (int2*)take((size_t)N_EDGES * 8);
    u32*   xwb     = (u32*)take((size_t)N_NODES * (NHID / 2) * 4);   // f16 packed
    u32*   hb      = (u32*)take((size_t)N_NODES * (NHID / 2) * 4);   // f16 packed
    u32*   hwb     = (u32*)take((size_t)N_NODES * (NCLASS / 2) * 4); // f16 packed

    zeroA_kernel<<<1, 256, 0, stream>>>(ghist);
    mega1_kernel<<<GEMM_BLOCKS + HIST_BLOCKS, 256, 0, stream>>>(x, W1, xwb, ei, ghist);
    scanA_kernel<<<1, NB, 0, stream>>>(ghist, bstart, gcursor);
    fillA_kernel<<<FILL_BLOCKS, 256, 0, stream>>>(ei, ew, gcursor, ebuf);
    sortB_kernel<<<NB, 256, 0, stream>>>(ebuf, bstart, ebuf2, row_ptr);

    agg1_kernel<<<(N_NODES + 3) / 4, 256, 0, stream>>>(xwb, row_ptr, ebuf2, hb);
    gemm2_kernel<<<GEMM_BLOCKS, 256, 0, stream>>>(hb, W2, hwb);
    agg2_kernel<<<(N_NODES * 64 + 255) / 256, 256, 0, stream>>>(hwb, row_ptr, ebuf2, out);
}

// Round 18
// 139.375 us; speedup vs baseline: 1.0953x; 1.0358x over previous
//
#include <hip/hip_runtime.h>
#include <hip/hip_fp16.h>

#define N_NODES 100000
#define N_EDGES 1600000
#define NFEAT 128
#define NHID 64
#define NCLASS 16

#define NPB 98                     // dst-nodes per bucket
#define NB 1024                    // ceil(100000 / 98) = 1021 -> pad to 1024
#define HIST_EPT 16
#define HIST_BLOCKS ((N_EDGES + 256 * HIST_EPT - 1) / (256 * HIST_EPT))  // 391
#define FILL_EPT 16
#define FILL_BLOCKS ((N_EDGES + 256 * FILL_EPT - 1) / (256 * FILL_EPT))  // 391
#define NTILES ((N_NODES + 15) / 16)            // 6250
#define GEMM_BLOCKS ((NTILES + 3) / 4)          // 1563

typedef unsigned int u32;
typedef __attribute__((ext_vector_type(8))) _Float16 f16x8;
typedef __attribute__((ext_vector_type(4))) float f32x4;

__device__ __forceinline__ __half2 u2h2(u32 u) { __half2 h; __builtin_memcpy(&h, &u, 4); return h; }
__device__ __forceinline__ u32 h22u(__half2 h) { u32 u; __builtin_memcpy(&u, &h, 4); return u; }
__device__ __forceinline__ u32 pack_h16(float a, float b) { return h22u(__floats2half2_rn(a, b)); }

// per-block edge-index dtype detection: odd u32 of first 64 int64 slots are all
// zero iff data is int64 (node ids < 2^31).
__device__ __forceinline__ int detect_i32(const void* ei) {
    u32 v = ((const u32*)ei)[2 * (threadIdx.x & 63) + 1];
    return (__ballot(v != 0) != 0ULL) ? 1 : 0;  // 1 => int32 data
}

__device__ __forceinline__ int load_idx(const void* ei, int flag, size_t pos) {
    return flag ? ((const int*)ei)[pos] : (int)((const long long*)ei)[pos];
}

// ---------- tiny zero of ghist (replaces rocclr fillBuffer dispatch) ----------
__global__ __launch_bounds__(256) void zeroA_kernel(int* __restrict__ ghist) {
    int t = threadIdx.x;
#pragma unroll
    for (int k = 0; k < NB / 256; ++k) ghist[t + k * 256] = 0;
}

// ---------- mega1: gemm1 (MFMA f16) blocks first, then histA blocks ----------
__global__ __launch_bounds__(256) void mega1_kernel(const float* __restrict__ X,
                                                    const float* __restrict__ W,
                                                    u32* __restrict__ Y,
                                                    const void* __restrict__ ei,
                                                    int* __restrict__ ghist) {
    __shared__ float Wsh[NFEAT * NHID];  // 32 KB (hist path reuses as int cnt[NB])
    int t = threadIdx.x;
    if (blockIdx.x < GEMM_BLOCKS) {
        for (int i = t; i < NFEAT * NHID; i += 256) Wsh[i] = W[i];
        __syncthreads();
        int wid = t >> 6;
        int lane = t & 63;
        int r = lane & 15, g = lane >> 4;
        int m0 = (blockIdx.x * 4 + wid) * 16;
        if (m0 >= N_NODES) return;

        f16x8 af[4][4];  // [ntile][ktile]
#pragma unroll
        for (int nt = 0; nt < 4; ++nt)
#pragma unroll
            for (int kt = 0; kt < 4; ++kt)
#pragma unroll
                for (int j = 0; j < 8; ++j)
                    af[nt][kt][j] = (_Float16)Wsh[(kt * 32 + g * 8 + j) * NHID + nt * 16 + r];

        const float* xr = X + (size_t)(m0 + r) * NFEAT + g * 8;
        f16x8 bfr[4];
#pragma unroll
        for (int kt = 0; kt < 4; ++kt) {
            float4 v0 = *(const float4*)(xr + kt * 32);
            float4 v1 = *(const float4*)(xr + kt * 32 + 4);
            bfr[kt][0] = (_Float16)v0.x; bfr[kt][1] = (_Float16)v0.y;
            bfr[kt][2] = (_Float16)v0.z; bfr[kt][3] = (_Float16)v0.w;
            bfr[kt][4] = (_Float16)v1.x; bfr[kt][5] = (_Float16)v1.y;
            bfr[kt][6] = (_Float16)v1.z; bfr[kt][7] = (_Float16)v1.w;
        }

        u32* yr = Y + (size_t)(m0 + r) * (NHID / 2);
#pragma unroll
        for (int nt = 0; nt < 4; ++nt) {
            f32x4 acc = {0.f, 0.f, 0.f, 0.f};
#pragma unroll
            for (int kt = 0; kt < 4; ++kt)
                acc = __builtin_amdgcn_mfma_f32_16x16x32_f16(af[nt][kt], bfr[kt], acc, 0, 0, 0);
            uint2 o;
            o.x = pack_h16(acc[0], acc[1]);
            o.y = pack_h16(acc[2], acc[3]);
            *(uint2*)(yr + nt * 8 + g * 2) = o;
        }
    } else {
        int* cnt = (int*)Wsh;
        int bid = blockIdx.x - GEMM_BLOCKS;
#pragma unroll
        for (int k = 0; k < NB / 256; ++k) cnt[t + k * 256] = 0;
        __syncthreads();
        int f = detect_i32(ei);
        int base = bid * 256 * HIST_EPT;
#pragma unroll
        for (int k = 0; k < HIST_EPT; ++k) {
            int e = base + k * 256 + t;
            if (e < N_EDGES) {
                int d = load_idx(ei, f, (size_t)N_EDGES + e);
                atomicAdd(&cnt[d / NPB], 1);
            }
        }
        __syncthreads();
#pragma unroll
        for (int k = 0; k < NB / 256; ++k)
            if (cnt[t + k * 256] > 0) atomicAdd(&ghist[t + k * 256], cnt[t + k * 256]);
    }
}

// single-block scan of NB bucket counts -> bstart (exclusive) + gcursor
__global__ __launch_bounds__(1024) void scanA_kernel(const int* __restrict__ ghist,
                                                     int* __restrict__ bstart,
                                                     int* __restrict__ gcursor) {
    __shared__ int lds[NB];
    int t = threadIdx.x;
    int own = ghist[t];
    lds[t] = own;
    __syncthreads();
    for (int off = 1; off < NB; off <<= 1) {
        int v = (t >= off) ? lds[t - off] : 0;
        __syncthreads();
        lds[t] += v;
        __syncthreads();
    }
    int excl = lds[t] - own;
    bstart[t] = excl;
    if (t == NB - 1) bstart[NB] = lds[NB - 1];
    gcursor[t] = excl;
}

// block-privatized bin scatter: {src | dstl<<20, w} into bucket-contiguous ebuf
__global__ __launch_bounds__(256) void fillA_kernel(const void* __restrict__ ei,
                                                    const float* __restrict__ ew,
                                                    int* __restrict__ gcursor,
                                                    int2* __restrict__ ebuf) {
    __shared__ int cnt[NB];
    __shared__ int base[NB];
    int t = threadIdx.x;
#pragma unroll
    for (int k = 0; k < NB / 256; ++k) cnt[t + k * 256] = 0;
    __syncthreads();
    int f = detect_i32(ei);
    int eb = blockIdx.x * 256 * FILL_EPT;
    int src[FILL_EPT], bin[FILL_EPT], rank[FILL_EPT];
    float w[FILL_EPT];
#pragma unroll
    for (int k = 0; k < FILL_EPT; ++k) {
        int e = eb + k * 256 + t;
        bin[k] = -1;
        if (e < N_EDGES) {
            int s = load_idx(ei, f, (size_t)e);
            int d = load_idx(ei, f, (size_t)N_EDGES + e);
            int b = d / NPB;
            src[k] = s | ((d - b * NPB) << 20);
            w[k] = ew[e];
            bin[k] = b;
            rank[k] = atomicAdd(&cnt[b], 1);
        }
    }
    __syncthreads();
#pragma unroll
    for (int k = 0; k < NB / 256; ++k)
        if (cnt[t + k * 256] > 0) base[t + k * 256] = atomicAdd(&gcursor[t + k * 256], cnt[t + k * 256]);
    __syncthreads();
#pragma unroll
    for (int k = 0; k < FILL_EPT; ++k) {
        if (bin[k] >= 0) {
            int pos = base[bin[k]] + rank[k];
            ebuf[pos] = make_int2(src[k], __float_as_int(w[k]));
        }
    }
}

// per-bucket counting sort -> exact CSR (ebuf2) + row_ptr
__global__ __launch_bounds__(256) void sortB_kernel(const int2* __restrict__ ebuf,
                                                    const int* __restrict__ bstart,
                                                    int2* __restrict__ ebuf2,
                                                    int* __restrict__ row_ptr) {
    __shared__ int cnt[NPB];
    __shared__ int sc[256];
    __shared__ int cur[NPB];
    int t = threadIdx.x, b = blockIdx.x;
    if (t < NPB) cnt[t] = 0;
    __syncthreads();
    int start = bstart[b], end = bstart[b + 1];
    for (int i = start + t; i < end; i += 256) {
        int dl = ((u32)ebuf[i].x) >> 20;
        atomicAdd(&cnt[dl], 1);
    }
    __syncthreads();
    int own = (t < NPB) ? cnt[t] : 0;
    sc[t] = own;
    __syncthreads();
    for (int off = 1; off < 256; off <<= 1) {
        int v = (t >= off) ? sc[t - off] : 0;
        __syncthreads();
        sc[t] += v;
        __syncthreads();
    }
    int excl = sc[t] - own;
    if (t < NPB) {
        cur[t] = excl;
        int node = b * NPB + t;
        if (node < N_NODES) row_ptr[node] = start + excl;
    }
    if (b == 0 && t == 0) row_ptr[N_NODES] = N_EDGES;
    __syncthreads();
    for (int i = start + t; i < end; i += 256) {
        int2 p = ebuf[i];
        int dl = ((u32)p.x) >> 20;
        int pos = start + atomicAdd(&cur[dl], 1);
        ebuf2[pos] = make_int2(p.x & 0xFFFFF, p.y);
    }
}

// ---------- gemm2 via MFMA f16: D = W2^T x h^T; B-frags load packed-f16 h ----------
__global__ __launch_bounds__(256) void gemm2_kernel(const u32* __restrict__ Hb,
                                                    const float* __restrict__ W,
                                                    u32* __restrict__ Y) {
    __shared__ float Wsh[NHID * NCLASS];  // 4 KB
    int t = threadIdx.x;
    for (int i = t; i < NHID * NCLASS; i += 256) Wsh[i] = W[i];
    __syncthreads();
    int wid = t >> 6;
    int lane = t & 63;
    int r = lane & 15, g = lane >> 4;
    int m0 = (blockIdx.x * 4 + wid) * 16;
    if (m0 >= N_NODES) return;

    f16x8 af[2];
#pragma unroll
    for (int kt = 0; kt < 2; ++kt)
#pragma unroll
        for (int j = 0; j < 8; ++j)
            af[kt][j] = (_Float16)Wsh[(kt * 32 + g * 8 + j) * NCLASS + r];

    const u32* hr = Hb + (size_t)(m0 + r) * (NHID / 2) + g * 4;
    union { uint4 u; f16x8 h; } b0, b1;
    b0.u = *(const uint4*)(hr + 0);
    b1.u = *(const uint4*)(hr + 16);

    f32x4 acc = {0.f, 0.f, 0.f, 0.f};
    acc = __builtin_amdgcn_mfma_f32_16x16x32_f16(af[0], b0.h, acc, 0, 0, 0);
    acc = __builtin_amdgcn_mfma_f32_16x16x32_f16(af[1], b1.h, acc, 0, 0, 0);

    u32* yr = Y + (size_t)(m0 + r) * (NCLASS / 2);
    uint2 o;
    o.x = pack_h16(acc[0], acc[1]);
    o.y = pack_h16(acc[2], acc[3]);
    *(uint2*)(yr + g * 2) = o;
}

// ---------- CSR aggregation with packed-f16 math ----------
// Layer 1: one wave per node; lane = sub*8+p (8 subs); lane gathers uint4
// (8 feats as 4 half2); 2-deep masked unroll -> 16 gathers in flight;
// butterfly over masks 8,16,32.
__global__ __launch_bounds__(256) void agg1_kernel(const u32* __restrict__ xwb,
                                                   const int* __restrict__ row_ptr,
                                                   const int2* __restrict__ ep,
                                                   u32* __restrict__ hb) {
    int t = blockIdx.x * 256 + threadIdx.x;
    int node = t >> 6;
    int lane = t & 63;
    int p = lane & 7;
    int sub = lane >> 3;
    if (node >= N_NODES) return;
    int start = row_ptr[node], end = row_ptr[node + 1];
    int last = end - 1;
    __half2 a0 = u2h2(0), a1 = u2h2(0), a2 = u2h2(0), a3 = u2h2(0);
    __half2 b0 = u2h2(0), b1 = u2h2(0), b2 = u2h2(0), b3 = u2h2(0);
    for (int i = start + sub; i < end; i += 16) {
        int j1 = min(i + 8, last);
        int2 p0 = ep[i];
        int2 p1 = ep[j1];
        uint4 u0 = *(const uint4*)(xwb + (size_t)p0.x * 32 + 4 * p);
        uint4 u1 = *(const uint4*)(xwb + (size_t)p1.x * 32 + 4 * p);
        float w0f = __int_as_float(p0.y);
        float w1f = (i + 8 < end) ? __int_as_float(p1.y) : 0.f;
        __half2 w0 = __half2half2(__float2half(w0f));
        __half2 w1 = __half2half2(__float2half(w1f));
        a0 = __hfma2(u2h2(u0.x), w0, a0); a1 = __hfma2(u2h2(u0.y), w0, a1);
        a2 = __hfma2(u2h2(u0.z), w0, a2); a3 = __hfma2(u2h2(u0.w), w0, a3);
        b0 = __hfma2(u2h2(u1.x), w1, b0); b1 = __hfma2(u2h2(u1.y), w1, b1);
        b2 = __hfma2(u2h2(u1.z), w1, b2); b3 = __hfma2(u2h2(u1.w), w1, b3);
    }
    a0 = __hadd2(a0, b0); a1 = __hadd2(a1, b1);
    a2 = __hadd2(a2, b2); a3 = __hadd2(a3, b3);
#pragma unroll
    for (int m = 8; m <= 32; m <<= 1) {
        a0 = __hadd2(a0, u2h2((u32)__shfl_xor((int)h22u(a0), m, 64)));
        a1 = __hadd2(a1, u2h2((u32)__shfl_xor((int)h22u(a1), m, 64)));
        a2 = __hadd2(a2, u2h2((u32)__shfl_xor((int)h22u(a2), m, 64)));
        a3 = __hadd2(a3, u2h2((u32)__shfl_xor((int)h22u(a3), m, 64)));
    }
    if (sub == 0) {
        float2 f0 = __half22float2(a0);
        float2 f1 = __half22float2(a1);
        float2 f2 = __half22float2(a2);
        float2 f3 = __half22float2(a3);
        uint4 o;
        o.x = pack_h16(fmaxf(f0.x, 0.f), fmaxf(f0.y, 0.f));
        o.y = pack_h16(fmaxf(f1.x, 0.f), fmaxf(f1.y, 0.f));
        o.z = pack_h16(fmaxf(f2.x, 0.f), fmaxf(f2.y, 0.f));
        o.w = pack_h16(fmaxf(f3.x, 0.f), fmaxf(f3.y, 0.f));
        *(uint4*)(hb + (size_t)node * 32 + 4 * p) = o;
    }
}

// Layer 2: one wave per node; lane = sub*2+p (32 subs); lane gathers uint4
// (8 classes); deg~16 completes in one un-masked pass; butterfly masks 2..32.
__global__ __launch_bounds__(256) void agg2_kernel(const u32* __restrict__ hwb,
                                                   const int* __restrict__ row_ptr,
                                                   const int2* __restrict__ ep,
                                                   float* __restrict__ out) {
    int t = blockIdx.x * 256 + threadIdx.x;
    int node = t >> 6;
    int lane = t & 63;
    int p = lane & 1;
    int sub = lane >> 1;
    if (node >= N_NODES) return;
    int start = row_ptr[node], end = row_ptr[node + 1];
    __half2 a0 = u2h2(0), a1 = u2h2(0), a2 = u2h2(0), a3 = u2h2(0);
    for (int i = start + sub; i < end; i += 32) {
        int2 pr = ep[i];
        uint4 u = *(const uint4*)(hwb + (size_t)pr.x * 8 + 4 * p);
        __half2 w = __half2half2(__float2half(__int_as_float(pr.y)));
        a0 = __hfma2(u2h2(u.x), w, a0); a1 = __hfma2(u2h2(u.y), w, a1);
        a2 = __hfma2(u2h2(u.z), w, a2); a3 = __hfma2(u2h2(u.w), w, a3);
    }
#pragma unroll
    for (int m = 2; m <= 32; m <<= 1) {
        a0 = __hadd2(a0, u2h2((u32)__shfl_xor((int)h22u(a0), m, 64)));
        a1 = __hadd2(a1, u2h2((u32)__shfl_xor((int)h22u(a1), m, 64)));
        a2 = __hadd2(a2, u2h2((u32)__shfl_xor((int)h22u(a2), m, 64)));
        a3 = __hadd2(a3, u2h2((u32)__shfl_xor((int)h22u(a3), m, 64)));
    }
    if (sub == 0) {
        float2 f0 = __half22float2(a0);
        float2 f1 = __half22float2(a1);
        float2 f2 = __half22float2(a2);
        float2 f3 = __half22float2(a3);
        float* op = out + (size_t)node * NCLASS + 8 * p;
        *(float4*)(op + 0) = make_float4(f0.x, f0.y, f1.x, f1.y);
        *(float4*)(op + 4) = make_float4(f2.x, f2.y, f3.x, f3.y);
    }
}

extern "C" void kernel_launch(void* const* d_in, const int* in_sizes, int n_in,
                              void* d_out, int out_size, void* d_ws, size_t ws_size,
                              hipStream_t stream) {
    const float* x  = (const float*)d_in[0];
    const void*  ei = d_in[1];
    const float* ew = (const float*)d_in[2];
    const float* W1 = (const float*)d_in[3];
    const float* W2 = (const float*)d_in[4];
    float* out = (float*)d_out;

    char* ws = (char*)d_ws;
    size_t off = 0;
    auto take = [&](size_t bytes) {
        char* p = ws + off;
        off += (bytes + 511) & ~(size_t)511;
        return p;
    };
    int*   ghist   = (int*)take(NB * 4);
    int*   bstart  = (int*)take((NB + 1) * 4);
    int*   gcursor = (int*)take(NB * 4);
    int*   row_ptr = (int*)take((size_t)(N_NODES + 1) * 4);
    int2*  ebuf    = (int2*)take((size_t)N_EDGES * 8);
    int2*  ebuf2   = (int2*)take((size_t)N_EDGES * 8);
    u32*   xwb     = (u32*)take((size_t)N_NODES * (NHID / 2) * 4);   // f16 packed
    u32*   hb      = (u32*)take((size_t)N_NODES * (NHID / 2) * 4);   // f16 packed
    u32*   hwb     = (u32*)take((size_t)N_NODES * (NCLASS / 2) * 4); // f16 packed

    zeroA_kernel<<<1, 256, 0, stream>>>(ghist);
    mega1_kernel<<<GEMM_BLOCKS + HIST_BLOCKS, 256, 0, stream>>>(x, W1, xwb, ei, ghist);
    scanA_kernel<<<1, NB, 0, stream>>>(ghist, bstart, gcursor);
    fillA_kernel<<<FILL_BLOCKS, 256, 0, stream>>>(ei, ew, gcursor, ebuf);
    sortB_kernel<<<NB, 256, 0, stream>>>(ebuf, bstart, ebuf2, row_ptr);

    agg1_kernel<<<(N_NODES * 64 + 255) / 256, 256, 0, stream>>>(xwb, row_ptr, ebuf2, hb);
    gemm2_kernel<<<GEMM_BLOCKS, 256, 0, stream>>>(hb, W2, hwb);
    agg2_kernel<<<(N_NODES * 64 + 255) / 256, 256, 0, stream>>>(hwb, row_ptr, ebuf2, out);
}